// Round 2
// baseline (290.150 us; speedup 1.0000x reference)
//
#include <hip/hip_runtime.h>
#include <hip/hip_bf16.h>
#include <cstdint>

typedef __bf16 bf16_t;
typedef __bf16 bf16x8 __attribute__((ext_vector_type(8)));
typedef __bf16 bf16x4 __attribute__((ext_vector_type(4)));
typedef float floatx4 __attribute__((ext_vector_type(4)));

typedef __attribute__((address_space(3))) uint32_t lds_u32_t;
typedef const __attribute__((address_space(1))) uint32_t g_u32_t;

#define MFMA_BF16(a, b, c) __builtin_amdgcn_mfma_f32_16x16x32_bf16((a), (b), (c), 0, 0, 0)

static constexpr int S = 1024;
static constexpr int HD = 64;

// ---------------- fp32 -> bf16 convert ----------------
struct ConvArgs {
  const float* src[7];
  bf16_t* dst[7];
  int n[7];
};

__global__ __launch_bounds__(256) void convert_kernel(ConvArgs a) {
  const int j = blockIdx.y;
  const float4* __restrict__ s = (const float4*)a.src[j];
  bf16x4* __restrict__ d = (bf16x4*)a.dst[j];
  const int n4 = a.n[j] >> 2;
  for (int i = blockIdx.x * blockDim.x + threadIdx.x; i < n4; i += gridDim.x * blockDim.x) {
    float4 v = s[i];
    bf16x4 o;
    o[0] = (bf16_t)v.x; o[1] = (bf16_t)v.y; o[2] = (bf16_t)v.z; o[3] = (bf16_t)v.w;
    d[i] = o;
  }
}

// ---------------- NT GEMM: C[m][n] = sum_k A[m][k] * B[n][k] (+bias) ----------------
// 128x128 block tile, BK=32, 4 waves each computing a 64x64 quadrant (4x4 16x16 frags).
// mode 0: out bf16 scattered to (b,h,s,hd); bias per col.   (Q, K projections)
// mode 1: out bf16 scattered to (b,h,hd,s); bias per row.   (V projection, A=Wv, B=z)
struct GemmCfg {
  const bf16_t* A;
  const bf16_t* Bm;
  void* out;
  const float* bias;
  int nbshift;  // log2(N/128)
  int mode;
};

__global__ __launch_bounds__(256) void gemm_nt_kernel(GemmCfg c0, GemmCfg c1, GemmCfg c2, int K) {
  GemmCfg cfg = (blockIdx.y == 0) ? c0 : (blockIdx.y == 1 ? c1 : c2);
  __shared__ bf16_t As[128 * 32];
  __shared__ bf16_t Bs[128 * 32];
  const int tid = threadIdx.x;
  const int wave = tid >> 6;
  const int lane = tid & 63;
  const int g = lane >> 4;
  const int cl = lane & 15;
  const int mq = (wave & 1) * 64;
  const int nq = (wave >> 1) * 64;
  const int nb = blockIdx.x & ((1 << cfg.nbshift) - 1);
  const int mb = blockIdx.x >> cfg.nbshift;
  const int m0 = mb * 128, n0 = nb * 128;

  const bf16_t* Ag = cfg.A + (size_t)(m0 + (tid >> 2)) * K + (tid & 3) * 8;
  const bf16_t* Bg = cfg.Bm + (size_t)(n0 + (tid >> 2)) * K + (tid & 3) * 8;

  floatx4 acc[4][4];
#pragma unroll
  for (int i = 0; i < 4; ++i)
#pragma unroll
    for (int j = 0; j < 4; ++j) acc[i][j] = floatx4{0.f, 0.f, 0.f, 0.f};

  const int kiters = K >> 5;
  for (int kt = 0; kt < kiters; ++kt) {
    __syncthreads();
    __builtin_amdgcn_global_load_lds((g_u32_t*)(const void*)Ag,
                                     (lds_u32_t*)(void*)&As[tid * 8], 16, 0, 0);
    __builtin_amdgcn_global_load_lds((g_u32_t*)(const void*)(Ag + (size_t)64 * K),
                                     (lds_u32_t*)(void*)&As[2048 + tid * 8], 16, 0, 0);
    __builtin_amdgcn_global_load_lds((g_u32_t*)(const void*)Bg,
                                     (lds_u32_t*)(void*)&Bs[tid * 8], 16, 0, 0);
    __builtin_amdgcn_global_load_lds((g_u32_t*)(const void*)(Bg + (size_t)64 * K),
                                     (lds_u32_t*)(void*)&Bs[2048 + tid * 8], 16, 0, 0);
    Ag += 32;
    Bg += 32;
    __syncthreads();

    bf16x8 af[4], bfr[4];
#pragma unroll
    for (int i = 0; i < 4; ++i) af[i] = *(const bf16x8*)&As[(mq + i * 16 + cl) * 32 + g * 8];
#pragma unroll
    for (int j = 0; j < 4; ++j) bfr[j] = *(const bf16x8*)&Bs[(nq + j * 16 + cl) * 32 + g * 8];
#pragma unroll
    for (int i = 0; i < 4; ++i)
#pragma unroll
      for (int j = 0; j < 4; ++j) acc[i][j] = MFMA_BF16(af[i], bfr[j], acc[i][j]);
  }

#pragma unroll
  for (int i = 0; i < 4; ++i) {
#pragma unroll
    for (int j = 0; j < 4; ++j) {
#pragma unroll
      for (int r = 0; r < 4; ++r) {
        const int m = m0 + mq + i * 16 + g * 4 + r;
        const int n = n0 + nq + j * 16 + cl;
        float v = acc[i][j][r];
        if (cfg.mode == 0) {
          v += cfg.bias[n];
          ((bf16_t*)cfg.out)[(size_t)((m >> 10) * 16 + (n >> 6)) * 65536 + (m & 1023) * 64 + (n & 63)] =
              (bf16_t)v;
        } else {
          v += cfg.bias[m];
          ((bf16_t*)cfg.out)[(size_t)((n >> 10) * 16 + (m >> 6)) * 65536 + (m & 63) * 1024 + (n & 1023)] =
              (bf16_t)v;
        }
      }
    }
  }
}

// ---------------- fused attention ----------------
// grid 1024 = 16 q-tiles(64) x 64 (b,h), laid out qt*64+bh so all q-tiles of one
// (b,h) land on XCD bh%8 (L2 locality for K/V). 4 waves/block, each wave owns
// 16 q rows. No __syncthreads: LDS P tile is per-wave private.
// out = (P@V)/rowsum(P) + mask@V, with P = exp(QK^T/32). Mask@V is accumulated
// in-kernel (flop-neutral vs a separate GEMM: each head needs only its hd slice).
__global__ __launch_bounds__(256, 4) void attn_kernel(const bf16_t* __restrict__ Q,
                                                      const bf16_t* __restrict__ Kb,
                                                      const bf16_t* __restrict__ Vt,
                                                      const bf16_t* __restrict__ Mk,
                                                      float* __restrict__ out) {
  __shared__ bf16_t Pbuf[4][16 * 136];  // stride 136 keeps rows 16B-aligned (272B)
  const int tid = threadIdx.x;
  const int wave = tid >> 6, lane = tid & 63;
  const int g = lane >> 4, cl = lane & 15;
  const int bh = blockIdx.x & 63, qt = blockIdx.x >> 6;
  const int q0 = qt * 64 + wave * 16;
  const bf16_t* Qp = Q + (size_t)bh * (S * HD);
  const bf16_t* Kp = Kb + (size_t)bh * (S * HD);
  const bf16_t* Vp = Vt + (size_t)bh * (S * HD);
  bf16_t* Pw = &Pbuf[wave][0];

  // Q A-frags direct from global: m=cl, k=g*8+j (16B contiguous)
  bf16x8 qf[2];
#pragma unroll
  for (int kc = 0; kc < 2; ++kc)
    qf[kc] = *(const bf16x8*)&Qp[(size_t)(q0 + cl) * HD + kc * 32 + g * 8];

  floatx4 o[4], o2[4];
  float dsum[4] = {0.f, 0.f, 0.f, 0.f};
#pragma unroll
  for (int nj = 0; nj < 4; ++nj) {
    o[nj] = floatx4{0.f, 0.f, 0.f, 0.f};
    o2[nj] = floatx4{0.f, 0.f, 0.f, 0.f};
  }

  for (int kt = 0; kt < 8; ++kt) {
    const int k0 = kt * 128;
    // S = Q @ K^T (keys = MFMA n-dim; K B-frags direct from global/L2)
    floatx4 sf[8];
#pragma unroll
    for (int nj = 0; nj < 8; ++nj) sf[nj] = floatx4{0.f, 0.f, 0.f, 0.f};
#pragma unroll
    for (int nj = 0; nj < 8; ++nj) {
      bf16x8 kf0 = *(const bf16x8*)&Kp[(size_t)(k0 + nj * 16 + cl) * HD + g * 8];
      bf16x8 kf1 = *(const bf16x8*)&Kp[(size_t)(k0 + nj * 16 + cl) * HD + 32 + g * 8];
      sf[nj] = MFMA_BF16(qf[0], kf0, sf[nj]);
      sf[nj] = MFMA_BF16(qf[1], kf1, sf[nj]);
    }
    // P = exp(S/32) -> fp32 row-sum (denominator) + per-wave LDS (C-layout write).
    // No max-subtraction needed: logits ~ N(0,0.25), exp cannot overflow here.
#pragma unroll
    for (int nj = 0; nj < 8; ++nj)
#pragma unroll
      for (int r = 0; r < 4; ++r) {
        float e = __expf(sf[nj][r] * 0.03125f);
        dsum[r] += e;
        Pw[(g * 4 + r) * 136 + nj * 16 + cl] = (bf16_t)e;
      }
    // O += P @ V ; O2 += mask @ V  (P A-frags from LDS; mask A-frags and V
    // B-frags direct from global/L2). mask@V is independent work that overlaps
    // the QK->exp->LDS chain of the next iteration.
#pragma unroll
    for (int kc = 0; kc < 4; ++kc) {
      bf16x8 pa = *(const bf16x8*)&Pw[cl * 136 + kc * 32 + g * 8];
      bf16x8 ma = *(const bf16x8*)&Mk[(size_t)(q0 + cl) * S + k0 + kc * 32 + g * 8];
#pragma unroll
      for (int nj = 0; nj < 4; ++nj) {
        bf16x8 vf = *(const bf16x8*)&Vp[(size_t)(nj * 16 + cl) * S + k0 + kc * 32 + g * 8];
        o[nj] = MFMA_BF16(pa, vf, o[nj]);
        o2[nj] = MFMA_BF16(ma, vf, o2[nj]);
      }
    }
  }

  // reduce dsum across the 16 cl lanes (stay within the g-group: masks 1,2,4,8)
#pragma unroll
  for (int r = 0; r < 4; ++r) {
#pragma unroll
    for (int m = 1; m < 16; m <<= 1) dsum[r] += __shfl_xor(dsum[r], m, 64);
  }

  const int b = bh >> 4, h = bh & 15;
#pragma unroll
  for (int r = 0; r < 4; ++r) {
    const float dinv = 1.0f / dsum[r];
    const int srow = q0 + g * 4 + r;
#pragma unroll
    for (int nj = 0; nj < 4; ++nj) {
      const int hd = nj * 16 + cl;
      out[((size_t)b * S + srow) * 1024 + h * HD + hd] = o[nj][r] * dinv + o2[nj][r];
    }
  }
}

extern "C" void kernel_launch(void* const* d_in, const int* in_sizes, int n_in,
                              void* d_out, int out_size, void* d_ws, size_t ws_size,
                              hipStream_t stream) {
  const float* x = (const float*)d_in[0];
  const float* y = (const float*)d_in[1];
  const float* z = (const float*)d_in[2];
  const float* mask = (const float*)d_in[3];
  const float* wq_w = (const float*)d_in[4];
  const float* wq_b = (const float*)d_in[5];
  const float* wk_w = (const float*)d_in[6];
  const float* wk_b = (const float*)d_in[7];
  const float* wv_w = (const float*)d_in[8];
  const float* wv_b = (const float*)d_in[9];

  uint8_t* ws = (uint8_t*)d_ws;
  const size_t MB = 1u << 20;
  bf16_t* Xb = (bf16_t*)(ws + 0 * MB);
  bf16_t* Yb = (bf16_t*)(ws + 8 * MB);
  bf16_t* Zb = (bf16_t*)(ws + 16 * MB);
  bf16_t* Wqb = (bf16_t*)(ws + 24 * MB);
  bf16_t* Wkb = (bf16_t*)(ws + 26 * MB);
  bf16_t* Wvb = (bf16_t*)(ws + 28 * MB);
  bf16_t* Mb = (bf16_t*)(ws + 30 * MB);
  bf16_t* Qb = (bf16_t*)(ws + 32 * MB);   // (b,h,s,hd) bf16
  bf16_t* Kb = (bf16_t*)(ws + 40 * MB);   // (b,h,s,hd) bf16
  bf16_t* Vtb = (bf16_t*)(ws + 48 * MB);  // (b,h,hd,s) bf16

  ConvArgs ca;
  ca.src[0] = x;    ca.dst[0] = Xb;  ca.n[0] = 4 * 1024 * 1024;
  ca.src[1] = y;    ca.dst[1] = Yb;  ca.n[1] = 4 * 1024 * 1024;
  ca.src[2] = z;    ca.dst[2] = Zb;  ca.n[2] = 4 * 1024 * 1024;
  ca.src[3] = wq_w; ca.dst[3] = Wqb; ca.n[3] = 1024 * 1024;
  ca.src[4] = wk_w; ca.dst[4] = Wkb; ca.n[4] = 1024 * 1024;
  ca.src[5] = wv_w; ca.dst[5] = Wvb; ca.n[5] = 1024 * 1024;
  ca.src[6] = mask; ca.dst[6] = Mb;  ca.n[6] = 1024 * 1024;
  convert_kernel<<<dim3(512, 7), 256, 0, stream>>>(ca);

  // Q = x@Wq^T (mode 0), K = y@Wk^T (mode 0), Vt = Wv@z^T (mode 1, transposed output)
  GemmCfg cq{Xb, Wqb, (void*)Qb, wq_b, 3, 0};
  GemmCfg ck{Yb, Wkb, (void*)Kb, wk_b, 3, 0};
  GemmCfg cv{Wvb, Zb, (void*)Vtb, wv_b, 5, 1};
  gemm_nt_kernel<<<dim3(256, 3), 256, 0, stream>>>(cq, ck, cv, 1024);

  attn_kernel<<<dim3(1024), 256, 0, stream>>>(Qb, Kb, Vtb, Mb, (float*)d_out);
}

// Round 3
// 192.198 us; speedup vs baseline: 1.5096x; 1.5096x over previous
//
#include <hip/hip_runtime.h>
#include <hip/hip_bf16.h>
#include <cstdint>

typedef __bf16 bf16_t;
typedef __bf16 bf16x8 __attribute__((ext_vector_type(8)));
typedef __bf16 bf16x4 __attribute__((ext_vector_type(4)));
typedef float floatx4 __attribute__((ext_vector_type(4)));

typedef __attribute__((address_space(3))) uint32_t lds_u32_t;
typedef const __attribute__((address_space(1))) uint32_t g_u32_t;

#define MFMA_BF16(a, b, c) __builtin_amdgcn_mfma_f32_16x16x32_bf16((a), (b), (c), 0, 0, 0)

static constexpr int S = 1024;
static constexpr int HD = 64;

// ---------------- fp32 -> bf16 convert ----------------
struct ConvArgs {
  const float* src[7];
  bf16_t* dst[7];
  int n[7];
};

__global__ __launch_bounds__(256) void convert_kernel(ConvArgs a) {
  const int j = blockIdx.y;
  const float4* __restrict__ s = (const float4*)a.src[j];
  bf16x4* __restrict__ d = (bf16x4*)a.dst[j];
  const int n4 = a.n[j] >> 2;
  for (int i = blockIdx.x * blockDim.x + threadIdx.x; i < n4; i += gridDim.x * blockDim.x) {
    float4 v = s[i];
    bf16x4 o;
    o[0] = (bf16_t)v.x; o[1] = (bf16_t)v.y; o[2] = (bf16_t)v.z; o[3] = (bf16_t)v.w;
    d[i] = o;
  }
}

// ---------------- NT GEMM: C[m][n] = sum_k A[m][k] * B[n][k] (+bias) ----------------
// 128x128 block tile, BK=32, 4 waves each computing a 64x64 quadrant (4x4 16x16 frags).
// mode 0: out bf16 scattered to (b,h,s,hd); bias per col.   (Q, K projections)
// mode 1: out bf16 scattered to (b,h,hd,s); bias per row.   (V projection, A=Wv, B=z)
struct GemmCfg {
  const bf16_t* A;
  const bf16_t* Bm;
  void* out;
  const float* bias;
  int nbshift;  // log2(N/128)
  int mode;
};

__global__ __launch_bounds__(256) void gemm_nt_kernel(GemmCfg c0, GemmCfg c1, GemmCfg c2, int K) {
  GemmCfg cfg = (blockIdx.y == 0) ? c0 : (blockIdx.y == 1 ? c1 : c2);
  __shared__ bf16_t As[128 * 32];
  __shared__ bf16_t Bs[128 * 32];
  const int tid = threadIdx.x;
  const int wave = tid >> 6;
  const int lane = tid & 63;
  const int g = lane >> 4;
  const int cl = lane & 15;
  const int mq = (wave & 1) * 64;
  const int nq = (wave >> 1) * 64;
  const int nb = blockIdx.x & ((1 << cfg.nbshift) - 1);
  const int mb = blockIdx.x >> cfg.nbshift;
  const int m0 = mb * 128, n0 = nb * 128;

  const bf16_t* Ag = cfg.A + (size_t)(m0 + (tid >> 2)) * K + (tid & 3) * 8;
  const bf16_t* Bg = cfg.Bm + (size_t)(n0 + (tid >> 2)) * K + (tid & 3) * 8;

  floatx4 acc[4][4];
#pragma unroll
  for (int i = 0; i < 4; ++i)
#pragma unroll
    for (int j = 0; j < 4; ++j) acc[i][j] = floatx4{0.f, 0.f, 0.f, 0.f};

  const int kiters = K >> 5;
  for (int kt = 0; kt < kiters; ++kt) {
    __syncthreads();
    __builtin_amdgcn_global_load_lds((g_u32_t*)(const void*)Ag,
                                     (lds_u32_t*)(void*)&As[tid * 8], 16, 0, 0);
    __builtin_amdgcn_global_load_lds((g_u32_t*)(const void*)(Ag + (size_t)64 * K),
                                     (lds_u32_t*)(void*)&As[2048 + tid * 8], 16, 0, 0);
    __builtin_amdgcn_global_load_lds((g_u32_t*)(const void*)Bg,
                                     (lds_u32_t*)(void*)&Bs[tid * 8], 16, 0, 0);
    __builtin_amdgcn_global_load_lds((g_u32_t*)(const void*)(Bg + (size_t)64 * K),
                                     (lds_u32_t*)(void*)&Bs[2048 + tid * 8], 16, 0, 0);
    Ag += 32;
    Bg += 32;
    __syncthreads();

    bf16x8 af[4], bfr[4];
#pragma unroll
    for (int i = 0; i < 4; ++i) af[i] = *(const bf16x8*)&As[(mq + i * 16 + cl) * 32 + g * 8];
#pragma unroll
    for (int j = 0; j < 4; ++j) bfr[j] = *(const bf16x8*)&Bs[(nq + j * 16 + cl) * 32 + g * 8];
#pragma unroll
    for (int i = 0; i < 4; ++i)
#pragma unroll
      for (int j = 0; j < 4; ++j) acc[i][j] = MFMA_BF16(af[i], bfr[j], acc[i][j]);
  }

#pragma unroll
  for (int i = 0; i < 4; ++i) {
#pragma unroll
    for (int j = 0; j < 4; ++j) {
#pragma unroll
      for (int r = 0; r < 4; ++r) {
        const int m = m0 + mq + i * 16 + g * 4 + r;
        const int n = n0 + nq + j * 16 + cl;
        float v = acc[i][j][r];
        if (cfg.mode == 0) {
          v += cfg.bias[n];
          ((bf16_t*)cfg.out)[(size_t)((m >> 10) * 16 + (n >> 6)) * 65536 + (m & 1023) * 64 + (n & 63)] =
              (bf16_t)v;
        } else {
          v += cfg.bias[m];
          ((bf16_t*)cfg.out)[(size_t)((n >> 10) * 16 + (m >> 6)) * 65536 + (m & 63) * 1024 + (n & 1023)] =
              (bf16_t)v;
        }
      }
    }
  }
}

// ---------------- fused attention, GEMM-style LDS staging ----------------
// grid 512 = 8 q-tiles(128) x 64 (b,h): all q-tiles of one bh land on XCD bh%8.
// Block: 128 q-rows, 4 waves x 32 q-rows. Per k-tile (128 keys):
//   stage K[128x64] and Vt[64x128] into LDS (global_load_lds w16, XOR-swizzled
//   chunks so ds_read_b128 frags spread across bank quads), 2-barrier m97 loop.
//   S^T = K@Q^T (Q stays in registers as B-frags), exp -> P (per-wave LDS,
//   packed b64 writes), then O += P@V and O2 += mask@V from LDS/global.
// out = O/rowsum(P) + O2. No max-subtraction: logits ~ N(0,0.25), exp safe.
__global__ __launch_bounds__(256, 2) void attn_kernel(const bf16_t* __restrict__ Q,
                                                      const bf16_t* __restrict__ Kb,
                                                      const bf16_t* __restrict__ Vt,
                                                      const bf16_t* __restrict__ Mk,
                                                      float* __restrict__ out) {
  __shared__ bf16_t Ks[128 * 64];        // 16 KB
  __shared__ bf16_t Vs[64 * 128];        // 16 KB
  __shared__ bf16_t Pbuf[4][32 * 136];   // 34 KB, stride 136 = 17x16B (aligned, quad-spread)
  const int tid = threadIdx.x;
  const int wave = tid >> 6, lane = tid & 63;
  const int g = lane >> 4, cl = lane & 15;
  const int bh = blockIdx.x & 63, qt = blockIdx.x >> 6;
  const int q0w = qt * 128 + wave * 32;
  const bf16_t* Qp = Q + (size_t)bh * (S * HD);
  const bf16_t* Kp = Kb + (size_t)bh * (S * HD);
  const bf16_t* Vp = Vt + (size_t)bh * (S * HD);
  bf16_t* Pw = &Pbuf[wave][0];

  // staging: thread tid fills LDS slot (i*256+tid)*16B; it FETCHES the global
  // chunk c = c' ^ (row&7) so readers find data chunk cw at slot cw ^ (row&7).
  const int krow = tid >> 3, kch = (tid & 7) ^ (krow & 7);
  const int vrow = tid >> 4, vch = (tid & 15) ^ (vrow & 7);
  const int sw = cl & 7;  // reader-side swizzle key (row&7 == cl&7 for 16-strided rows)

  // Q B-frags, resident in registers for the whole kernel
  bf16x8 qf[2][2];
#pragma unroll
  for (int nj = 0; nj < 2; ++nj)
#pragma unroll
    for (int kc = 0; kc < 2; ++kc)
      qf[nj][kc] = *(const bf16x8*)&Qp[(size_t)(q0w + nj * 16 + cl) * HD + kc * 32 + g * 8];

  floatx4 o[2][4], o2[2][4];
#pragma unroll
  for (int mi = 0; mi < 2; ++mi)
#pragma unroll
    for (int nj = 0; nj < 4; ++nj) {
      o[mi][nj] = floatx4{0.f, 0.f, 0.f, 0.f};
      o2[mi][nj] = floatx4{0.f, 0.f, 0.f, 0.f};
    }
  float dsq[2] = {0.f, 0.f};

  for (int kt = 0; kt < 8; ++kt) {
    const int k0 = kt * 128;
    __syncthreads();
#pragma unroll
    for (int i = 0; i < 4; ++i)
      __builtin_amdgcn_global_load_lds(
          (g_u32_t*)(const void*)&Kp[(size_t)(k0 + i * 32 + krow) * HD + kch * 8],
          (lds_u32_t*)(void*)&Ks[(i * 256 + tid) * 8], 16, 0, 0);
#pragma unroll
    for (int i = 0; i < 4; ++i)
      __builtin_amdgcn_global_load_lds(
          (g_u32_t*)(const void*)&Vp[(size_t)(i * 16 + vrow) * S + k0 + vch * 8],
          (lds_u32_t*)(void*)&Vs[(i * 256 + tid) * 8], 16, 0, 0);
    __syncthreads();

    // S^T[k][q] = K @ Q^T ; exp ; packed b64 write into P[q][k]
#pragma unroll
    for (int mi = 0; mi < 8; ++mi) {
      bf16x8 kf0 = *(const bf16x8*)&Ks[(mi * 16 + cl) * 64 + ((0 + g) ^ sw) * 8];
      bf16x8 kf1 = *(const bf16x8*)&Ks[(mi * 16 + cl) * 64 + ((4 + g) ^ sw) * 8];
      floatx4 s0 = floatx4{0.f, 0.f, 0.f, 0.f}, s1 = floatx4{0.f, 0.f, 0.f, 0.f};
      s0 = MFMA_BF16(kf0, qf[0][0], s0);
      s0 = MFMA_BF16(kf1, qf[0][1], s0);
      s1 = MFMA_BF16(kf0, qf[1][0], s1);
      s1 = MFMA_BF16(kf1, qf[1][1], s1);
      bf16x4 p0, p1;
#pragma unroll
      for (int r = 0; r < 4; ++r) {
        float e0 = __expf(s0[r] * 0.03125f);
        float e1 = __expf(s1[r] * 0.03125f);
        dsq[0] += e0;
        dsq[1] += e1;
        p0[r] = (bf16_t)e0;
        p1[r] = (bf16_t)e1;
      }
      *(bf16x4*)&Pw[(cl)*136 + mi * 16 + g * 4] = p0;
      *(bf16x4*)&Pw[(16 + cl) * 136 + mi * 16 + g * 4] = p1;
    }

    // O += P @ V ; O2 += mask @ V
#pragma unroll
    for (int kc = 0; kc < 4; ++kc) {
      bf16x8 pa0 = *(const bf16x8*)&Pw[cl * 136 + kc * 32 + g * 8];
      bf16x8 pa1 = *(const bf16x8*)&Pw[(16 + cl) * 136 + kc * 32 + g * 8];
      bf16x8 ma0 = *(const bf16x8*)&Mk[(size_t)(q0w + cl) * S + k0 + kc * 32 + g * 8];
      bf16x8 ma1 = *(const bf16x8*)&Mk[(size_t)(q0w + 16 + cl) * S + k0 + kc * 32 + g * 8];
#pragma unroll
      for (int nj = 0; nj < 4; ++nj) {
        bf16x8 vf = *(const bf16x8*)&Vs[(nj * 16 + cl) * 128 + ((kc * 4 + g) ^ sw) * 8];
        o[0][nj] = MFMA_BF16(pa0, vf, o[0][nj]);
        o[1][nj] = MFMA_BF16(pa1, vf, o[1][nj]);
        o2[0][nj] = MFMA_BF16(ma0, vf, o2[0][nj]);
        o2[1][nj] = MFMA_BF16(ma1, vf, o2[1][nj]);
      }
    }
  }

  // denominator: lane (g,cl) holds partial sums for q=nj*16+cl over its k-slice;
  // combine the 4 g-copies, then redistribute to the C-layout rows via shfl.
#pragma unroll
  for (int nj = 0; nj < 2; ++nj) {
    dsq[nj] += __shfl_xor(dsq[nj], 16, 64);
    dsq[nj] += __shfl_xor(dsq[nj], 32, 64);
  }

  const int b = bh >> 4, h = bh & 15;
#pragma unroll
  for (int mi = 0; mi < 2; ++mi) {
#pragma unroll
    for (int r = 0; r < 4; ++r) {
      float dv = __shfl(dsq[mi], g * 4 + r, 64);  // lane g*4+r holds denom(q = mi*16+g*4+r)
      float dinv = 1.0f / dv;
      const int srow = q0w + mi * 16 + g * 4 + r;
#pragma unroll
      for (int nj = 0; nj < 4; ++nj) {
        const int hd = nj * 16 + cl;
        out[((size_t)b * S + srow) * 1024 + h * HD + hd] = o[mi][nj][r] * dinv + o2[mi][nj][r];
      }
    }
  }
}

extern "C" void kernel_launch(void* const* d_in, const int* in_sizes, int n_in,
                              void* d_out, int out_size, void* d_ws, size_t ws_size,
                              hipStream_t stream) {
  const float* x = (const float*)d_in[0];
  const float* y = (const float*)d_in[1];
  const float* z = (const float*)d_in[2];
  const float* mask = (const float*)d_in[3];
  const float* wq_w = (const float*)d_in[4];
  const float* wq_b = (const float*)d_in[5];
  const float* wk_w = (const float*)d_in[6];
  const float* wk_b = (const float*)d_in[7];
  const float* wv_w = (const float*)d_in[8];
  const float* wv_b = (const float*)d_in[9];

  uint8_t* ws = (uint8_t*)d_ws;
  const size_t MB = 1u << 20;
  bf16_t* Xb = (bf16_t*)(ws + 0 * MB);
  bf16_t* Yb = (bf16_t*)(ws + 8 * MB);
  bf16_t* Zb = (bf16_t*)(ws + 16 * MB);
  bf16_t* Wqb = (bf16_t*)(ws + 24 * MB);
  bf16_t* Wkb = (bf16_t*)(ws + 26 * MB);
  bf16_t* Wvb = (bf16_t*)(ws + 28 * MB);
  bf16_t* Mb = (bf16_t*)(ws + 30 * MB);
  bf16_t* Qb = (bf16_t*)(ws + 32 * MB);   // (b,h,s,hd) bf16
  bf16_t* Kb = (bf16_t*)(ws + 40 * MB);   // (b,h,s,hd) bf16
  bf16_t* Vtb = (bf16_t*)(ws + 48 * MB);  // (b,h,hd,s) bf16

  ConvArgs ca;
  ca.src[0] = x;    ca.dst[0] = Xb;  ca.n[0] = 4 * 1024 * 1024;
  ca.src[1] = y;    ca.dst[1] = Yb;  ca.n[1] = 4 * 1024 * 1024;
  ca.src[2] = z;    ca.dst[2] = Zb;  ca.n[2] = 4 * 1024 * 1024;
  ca.src[3] = wq_w; ca.dst[3] = Wqb; ca.n[3] = 1024 * 1024;
  ca.src[4] = wk_w; ca.dst[4] = Wkb; ca.n[4] = 1024 * 1024;
  ca.src[5] = wv_w; ca.dst[5] = Wvb; ca.n[5] = 1024 * 1024;
  ca.src[6] = mask; ca.dst[6] = Mb;  ca.n[6] = 1024 * 1024;
  convert_kernel<<<dim3(512, 7), 256, 0, stream>>>(ca);

  // Q = x@Wq^T (mode 0), K = y@Wk^T (mode 0), Vt = Wv@z^T (mode 1, transposed output)
  GemmCfg cq{Xb, Wqb, (void*)Qb, wq_b, 3, 0};
  GemmCfg ck{Yb, Wkb, (void*)Kb, wk_b, 3, 0};
  GemmCfg cv{Wvb, Zb, (void*)Vtb, wv_b, 5, 1};
  gemm_nt_kernel<<<dim3(256, 3), 256, 0, stream>>>(cq, ck, cv, 1024);

  attn_kernel<<<dim3(512), 256, 0, stream>>>(Qb, Kb, Vtb, Mb, (float*)d_out);
}

// Round 4
// 182.319 us; speedup vs baseline: 1.5914x; 1.0542x over previous
//
#include <hip/hip_runtime.h>
#include <hip/hip_bf16.h>
#include <cstdint>

typedef __bf16 bf16_t;
typedef __bf16 bf16x8 __attribute__((ext_vector_type(8)));
typedef __bf16 bf16x4 __attribute__((ext_vector_type(4)));
typedef float floatx4 __attribute__((ext_vector_type(4)));

typedef __attribute__((address_space(3))) uint32_t lds_u32_t;
typedef const __attribute__((address_space(1))) uint32_t g_u32_t;

#define MFMA_BF16(a, b, c) __builtin_amdgcn_mfma_f32_16x16x32_bf16((a), (b), (c), 0, 0, 0)

static constexpr int S = 1024;
static constexpr int HD = 64;

// ---------------- fp32 -> bf16 convert ----------------
struct ConvArgs {
  const float* src[7];
  bf16_t* dst[7];
  int n[7];
};

__global__ __launch_bounds__(256) void convert_kernel(ConvArgs a) {
  const int j = blockIdx.y;
  const float4* __restrict__ s = (const float4*)a.src[j];
  bf16x4* __restrict__ d = (bf16x4*)a.dst[j];
  const int n4 = a.n[j] >> 2;
  for (int i = blockIdx.x * blockDim.x + threadIdx.x; i < n4; i += gridDim.x * blockDim.x) {
    float4 v = s[i];
    bf16x4 o;
    o[0] = (bf16_t)v.x; o[1] = (bf16_t)v.y; o[2] = (bf16_t)v.z; o[3] = (bf16_t)v.w;
    d[i] = o;
  }
}

// ---------------- NT GEMM: C[m][n] = sum_k A[m][k] * B[n][k] (+bias) ----------------
// 128x128 tile, BK=64 (16 two-barrier iters), 4 waves x 64x64 quadrant.
// XCD-aware mapping: mode 0 (Q,K: A=4096 rows big) -> each XCD owns 4 mb + all nb
// (per-XCD: 1 MB A distinct + 2 MB weights, fits 4 MB L2). mode 1 (V: B big) ->
// each XCD owns 4 nb + all mb. Epilogue repacks C through LDS for 16B stores.
// mode 0: out bf16 (b,h,s,hd), bias per col. mode 1: out bf16 (b,h,hd,s), bias per row.
struct GemmCfg {
  const bf16_t* A;
  const bf16_t* Bm;
  void* out;
  const float* bias;
  int mode;
};

union GemmSmem {
  struct { bf16_t A[128 * 64]; bf16_t B[128 * 64]; } ab;  // 32 KB
  bf16_t C[128 * 136];                                    // 34 KB
};

__global__ __launch_bounds__(256, 2) void gemm_nt_kernel(GemmCfg c0, GemmCfg c1, GemmCfg c2, int K) {
  GemmCfg cfg = (blockIdx.y == 0) ? c0 : (blockIdx.y == 1 ? c1 : c2);
  __shared__ GemmSmem u;
  __shared__ float bias_s[128];
  const int tid = threadIdx.x;
  const int wave = tid >> 6;
  const int lane = tid & 63;
  const int g = lane >> 4;
  const int cl = lane & 15;
  const int mq = (wave & 1) * 64;
  const int nq = (wave >> 1) * 64;

  const int xcd = blockIdx.x & 7, idx = blockIdx.x >> 3;
  int mb, nb;
  if (cfg.mode == 0) { mb = xcd * 4 + (idx & 3); nb = idx >> 2; }
  else               { nb = xcd * 4 + (idx & 3); mb = idx >> 2; }
  const int m0 = mb * 128, n0 = nb * 128;

  if (tid < 128) bias_s[tid] = cfg.bias[(cfg.mode == 0 ? n0 : m0) + tid];

  // staging: thread tid covers row (tid>>3), col-chunk (tid&7) of a 32-row slab
  const bf16_t* Ag = cfg.A + (size_t)(m0 + (tid >> 3)) * K + (tid & 7) * 8;
  const bf16_t* Bg = cfg.Bm + (size_t)(n0 + (tid >> 3)) * K + (tid & 7) * 8;

  floatx4 acc[4][4];
#pragma unroll
  for (int i = 0; i < 4; ++i)
#pragma unroll
    for (int j = 0; j < 4; ++j) acc[i][j] = floatx4{0.f, 0.f, 0.f, 0.f};

  const int kiters = K >> 6;
  for (int kt = 0; kt < kiters; ++kt) {
    __syncthreads();
#pragma unroll
    for (int i = 0; i < 4; ++i) {
      __builtin_amdgcn_global_load_lds((g_u32_t*)(const void*)(Ag + (size_t)(i * 32) * K),
                                       (lds_u32_t*)(void*)&u.ab.A[(i * 256 + tid) * 8], 16, 0, 0);
      __builtin_amdgcn_global_load_lds((g_u32_t*)(const void*)(Bg + (size_t)(i * 32) * K),
                                       (lds_u32_t*)(void*)&u.ab.B[(i * 256 + tid) * 8], 16, 0, 0);
    }
    Ag += 64;
    Bg += 64;
    __syncthreads();

#pragma unroll
    for (int kc = 0; kc < 2; ++kc) {
      bf16x8 af[4], bfr[4];
#pragma unroll
      for (int i = 0; i < 4; ++i)
        af[i] = *(const bf16x8*)&u.ab.A[(mq + i * 16 + cl) * 64 + kc * 32 + g * 8];
#pragma unroll
      for (int j = 0; j < 4; ++j)
        bfr[j] = *(const bf16x8*)&u.ab.B[(nq + j * 16 + cl) * 64 + kc * 32 + g * 8];
#pragma unroll
      for (int i = 0; i < 4; ++i)
#pragma unroll
        for (int j = 0; j < 4; ++j) acc[i][j] = MFMA_BF16(af[i], bfr[j], acc[i][j]);
    }
  }

  // epilogue: quadrants -> LDS (with bias), then cooperative 16B coalesced stores
  __syncthreads();
#pragma unroll
  for (int i = 0; i < 4; ++i)
#pragma unroll
    for (int j = 0; j < 4; ++j)
#pragma unroll
      for (int r = 0; r < 4; ++r) {
        const int ml = mq + i * 16 + g * 4 + r;
        const int nl = nq + j * 16 + cl;
        float v = acc[i][j][r] + bias_s[cfg.mode == 0 ? nl : ml];
        u.C[ml * 136 + nl] = (bf16_t)v;
      }
  __syncthreads();
#pragma unroll
  for (int it = 0; it < 8; ++it) {
    const int ix = it * 256 + tid;
    const int ml = ix >> 4, nc = ix & 15;
    bf16x8 val = *(const bf16x8*)&u.C[ml * 136 + nc * 8];
    const int m = m0 + ml, n = n0 + nc * 8;
    size_t addr;
    if (cfg.mode == 0)
      addr = (size_t)((m >> 10) * 16 + (n >> 6)) * 65536 + (m & 1023) * 64 + (n & 63);
    else
      addr = (size_t)((n >> 10) * 16 + (m >> 6)) * 65536 + (m & 63) * 1024 + (n & 1023);
    *(bf16x8*)&((bf16_t*)cfg.out)[addr] = val;
  }
}

// ---------------- fused attention, GEMM-style LDS staging ----------------
// grid 512 = 8 q-tiles(128) x 64 (b,h): all q-tiles of one bh land on XCD bh%8.
// Block: 128 q-rows, 4 waves x 32 q-rows. Per k-tile (128 keys):
//   stage K[128x64] and Vt[64x128] into LDS (global_load_lds w16, XOR-swizzled
//   chunks so ds_read_b128 frags spread across bank quads), 2-barrier m97 loop.
//   S^T = K@Q^T (Q stays in registers as B-frags), exp -> P (per-wave LDS,
//   packed b64 writes), then O += P@V and O2 += mask@V from LDS/global.
// out = O/rowsum(P) + O2. No max-subtraction: logits ~ N(0,0.25), exp safe.
__global__ __launch_bounds__(256, 2) void attn_kernel(const bf16_t* __restrict__ Q,
                                                      const bf16_t* __restrict__ Kb,
                                                      const bf16_t* __restrict__ Vt,
                                                      const bf16_t* __restrict__ Mk,
                                                      float* __restrict__ out) {
  __shared__ bf16_t Ks[128 * 64];        // 16 KB
  __shared__ bf16_t Vs[64 * 128];        // 16 KB
  __shared__ bf16_t Pbuf[4][32 * 136];   // 34 KB, stride 136 = 17x16B (aligned, quad-spread)
  const int tid = threadIdx.x;
  const int wave = tid >> 6, lane = tid & 63;
  const int g = lane >> 4, cl = lane & 15;
  const int bh = blockIdx.x & 63, qt = blockIdx.x >> 6;
  const int q0w = qt * 128 + wave * 32;
  const bf16_t* Qp = Q + (size_t)bh * (S * HD);
  const bf16_t* Kp = Kb + (size_t)bh * (S * HD);
  const bf16_t* Vp = Vt + (size_t)bh * (S * HD);
  bf16_t* Pw = &Pbuf[wave][0];

  // staging: thread tid fills LDS slot (i*256+tid)*16B; it FETCHES the global
  // chunk c = c' ^ (row&7) so readers find data chunk cw at slot cw ^ (row&7).
  const int krow = tid >> 3, kch = (tid & 7) ^ (krow & 7);
  const int vrow = tid >> 4, vch = (tid & 15) ^ (vrow & 7);
  const int sw = cl & 7;  // reader-side swizzle key (row&7 == cl&7 for 16-strided rows)

  // Q B-frags, resident in registers for the whole kernel
  bf16x8 qf[2][2];
#pragma unroll
  for (int nj = 0; nj < 2; ++nj)
#pragma unroll
    for (int kc = 0; kc < 2; ++kc)
      qf[nj][kc] = *(const bf16x8*)&Qp[(size_t)(q0w + nj * 16 + cl) * HD + kc * 32 + g * 8];

  floatx4 o[2][4], o2[2][4];
#pragma unroll
  for (int mi = 0; mi < 2; ++mi)
#pragma unroll
    for (int nj = 0; nj < 4; ++nj) {
      o[mi][nj] = floatx4{0.f, 0.f, 0.f, 0.f};
      o2[mi][nj] = floatx4{0.f, 0.f, 0.f, 0.f};
    }
  float dsq[2] = {0.f, 0.f};

  for (int kt = 0; kt < 8; ++kt) {
    const int k0 = kt * 128;
    __syncthreads();
#pragma unroll
    for (int i = 0; i < 4; ++i)
      __builtin_amdgcn_global_load_lds(
          (g_u32_t*)(const void*)&Kp[(size_t)(k0 + i * 32 + krow) * HD + kch * 8],
          (lds_u32_t*)(void*)&Ks[(i * 256 + tid) * 8], 16, 0, 0);
#pragma unroll
    for (int i = 0; i < 4; ++i)
      __builtin_amdgcn_global_load_lds(
          (g_u32_t*)(const void*)&Vp[(size_t)(i * 16 + vrow) * S + k0 + vch * 8],
          (lds_u32_t*)(void*)&Vs[(i * 256 + tid) * 8], 16, 0, 0);
    __syncthreads();

    // S^T[k][q] = K @ Q^T ; exp ; packed b64 write into P[q][k]
#pragma unroll
    for (int mi = 0; mi < 8; ++mi) {
      bf16x8 kf0 = *(const bf16x8*)&Ks[(mi * 16 + cl) * 64 + ((0 + g) ^ sw) * 8];
      bf16x8 kf1 = *(const bf16x8*)&Ks[(mi * 16 + cl) * 64 + ((4 + g) ^ sw) * 8];
      floatx4 s0 = floatx4{0.f, 0.f, 0.f, 0.f}, s1 = floatx4{0.f, 0.f, 0.f, 0.f};
      s0 = MFMA_BF16(kf0, qf[0][0], s0);
      s0 = MFMA_BF16(kf1, qf[0][1], s0);
      s1 = MFMA_BF16(kf0, qf[1][0], s1);
      s1 = MFMA_BF16(kf1, qf[1][1], s1);
      bf16x4 p0, p1;
#pragma unroll
      for (int r = 0; r < 4; ++r) {
        float e0 = __expf(s0[r] * 0.03125f);
        float e1 = __expf(s1[r] * 0.03125f);
        dsq[0] += e0;
        dsq[1] += e1;
        p0[r] = (bf16_t)e0;
        p1[r] = (bf16_t)e1;
      }
      *(bf16x4*)&Pw[(cl)*136 + mi * 16 + g * 4] = p0;
      *(bf16x4*)&Pw[(16 + cl) * 136 + mi * 16 + g * 4] = p1;
    }

    // O += P @ V ; O2 += mask @ V
#pragma unroll
    for (int kc = 0; kc < 4; ++kc) {
      bf16x8 pa0 = *(const bf16x8*)&Pw[cl * 136 + kc * 32 + g * 8];
      bf16x8 pa1 = *(const bf16x8*)&Pw[(16 + cl) * 136 + kc * 32 + g * 8];
      bf16x8 ma0 = *(const bf16x8*)&Mk[(size_t)(q0w + cl) * S + k0 + kc * 32 + g * 8];
      bf16x8 ma1 = *(const bf16x8*)&Mk[(size_t)(q0w + 16 + cl) * S + k0 + kc * 32 + g * 8];
#pragma unroll
      for (int nj = 0; nj < 4; ++nj) {
        bf16x8 vf = *(const bf16x8*)&Vs[(nj * 16 + cl) * 128 + ((kc * 4 + g) ^ sw) * 8];
        o[0][nj] = MFMA_BF16(pa0, vf, o[0][nj]);
        o[1][nj] = MFMA_BF16(pa1, vf, o[1][nj]);
        o2[0][nj] = MFMA_BF16(ma0, vf, o2[0][nj]);
        o2[1][nj] = MFMA_BF16(ma1, vf, o2[1][nj]);
      }
    }
  }

  // denominator: lane (g,cl) holds partial sums for q=nj*16+cl over its k-slice;
  // combine the 4 g-copies, then redistribute to the C-layout rows via shfl.
#pragma unroll
  for (int nj = 0; nj < 2; ++nj) {
    dsq[nj] += __shfl_xor(dsq[nj], 16, 64);
    dsq[nj] += __shfl_xor(dsq[nj], 32, 64);
  }

  const int b = bh >> 4, h = bh & 15;
#pragma unroll
  for (int mi = 0; mi < 2; ++mi) {
#pragma unroll
    for (int r = 0; r < 4; ++r) {
      float dv = __shfl(dsq[mi], g * 4 + r, 64);  // lane g*4+r holds denom(q = mi*16+g*4+r)
      float dinv = 1.0f / dv;
      const int srow = q0w + mi * 16 + g * 4 + r;
#pragma unroll
      for (int nj = 0; nj < 4; ++nj) {
        const int hd = nj * 16 + cl;
        out[((size_t)b * S + srow) * 1024 + h * HD + hd] = o[mi][nj][r] * dinv + o2[mi][nj][r];
      }
    }
  }
}

extern "C" void kernel_launch(void* const* d_in, const int* in_sizes, int n_in,
                              void* d_out, int out_size, void* d_ws, size_t ws_size,
                              hipStream_t stream) {
  const float* x = (const float*)d_in[0];
  const float* y = (const float*)d_in[1];
  const float* z = (const float*)d_in[2];
  const float* mask = (const float*)d_in[3];
  const float* wq_w = (const float*)d_in[4];
  const float* wq_b = (const float*)d_in[5];
  const float* wk_w = (const float*)d_in[6];
  const float* wk_b = (const float*)d_in[7];
  const float* wv_w = (const float*)d_in[8];
  const float* wv_b = (const float*)d_in[9];

  uint8_t* ws = (uint8_t*)d_ws;
  const size_t MB = 1u << 20;
  bf16_t* Xb = (bf16_t*)(ws + 0 * MB);
  bf16_t* Yb = (bf16_t*)(ws + 8 * MB);
  bf16_t* Zb = (bf16_t*)(ws + 16 * MB);
  bf16_t* Wqb = (bf16_t*)(ws + 24 * MB);
  bf16_t* Wkb = (bf16_t*)(ws + 26 * MB);
  bf16_t* Wvb = (bf16_t*)(ws + 28 * MB);
  bf16_t* Mb = (bf16_t*)(ws + 30 * MB);
  bf16_t* Qb = (bf16_t*)(ws + 32 * MB);   // (b,h,s,hd) bf16
  bf16_t* Kb = (bf16_t*)(ws + 40 * MB);   // (b,h,s,hd) bf16
  bf16_t* Vtb = (bf16_t*)(ws + 48 * MB);  // (b,h,hd,s) bf16

  ConvArgs ca;
  ca.src[0] = x;    ca.dst[0] = Xb;  ca.n[0] = 4 * 1024 * 1024;
  ca.src[1] = y;    ca.dst[1] = Yb;  ca.n[1] = 4 * 1024 * 1024;
  ca.src[2] = z;    ca.dst[2] = Zb;  ca.n[2] = 4 * 1024 * 1024;
  ca.src[3] = wq_w; ca.dst[3] = Wqb; ca.n[3] = 1024 * 1024;
  ca.src[4] = wk_w; ca.dst[4] = Wkb; ca.n[4] = 1024 * 1024;
  ca.src[5] = wv_w; ca.dst[5] = Wvb; ca.n[5] = 1024 * 1024;
  ca.src[6] = mask; ca.dst[6] = Mb;  ca.n[6] = 1024 * 1024;
  convert_kernel<<<dim3(512, 7), 256, 0, stream>>>(ca);

  // Q = x@Wq^T (mode 0), K = y@Wk^T (mode 0), Vt = Wv@z^T (mode 1, transposed output)
  GemmCfg cq{Xb, Wqb, (void*)Qb, wq_b, 0};
  GemmCfg ck{Yb, Wkb, (void*)Kb, wk_b, 0};
  GemmCfg cv{Wvb, Zb, (void*)Vtb, wv_b, 1};
  gemm_nt_kernel<<<dim3(256, 3), 256, 0, stream>>>(cq, ck, cv, 1024);

  attn_kernel<<<dim3(512), 256, 0, stream>>>(Qb, Kb, Vtb, Mb, (float*)d_out);
}

// Round 5
// 178.222 us; speedup vs baseline: 1.6280x; 1.0230x over previous
//
#include <hip/hip_runtime.h>
#include <hip/hip_bf16.h>
#include <cstdint>

typedef __bf16 bf16_t;
typedef __bf16 bf16x8 __attribute__((ext_vector_type(8)));
typedef __bf16 bf16x4 __attribute__((ext_vector_type(4)));
typedef float floatx4 __attribute__((ext_vector_type(4)));

typedef __attribute__((address_space(3))) uint32_t lds_u32_t;
typedef const __attribute__((address_space(1))) uint32_t g_u32_t;

#define MFMA_BF16(a, b, c) __builtin_amdgcn_mfma_f32_16x16x32_bf16((a), (b), (c), 0, 0, 0)

static constexpr int S = 1024;
static constexpr int HD = 64;

// ---------------- fp32 -> bf16 convert ----------------
struct ConvArgs {
  const float* src[7];
  bf16_t* dst[7];
  int n[7];
};

__global__ __launch_bounds__(256) void convert_kernel(ConvArgs a) {
  const int j = blockIdx.y;
  const float4* __restrict__ s = (const float4*)a.src[j];
  bf16x4* __restrict__ d = (bf16x4*)a.dst[j];
  const int n4 = a.n[j] >> 2;
  for (int i = blockIdx.x * blockDim.x + threadIdx.x; i < n4; i += gridDim.x * blockDim.x) {
    float4 v = s[i];
    bf16x4 o;
    o[0] = (bf16_t)v.x; o[1] = (bf16_t)v.y; o[2] = (bf16_t)v.z; o[3] = (bf16_t)v.w;
    d[i] = o;
  }
}

// ---------------- NT GEMM: C[m][n] = sum_k A[m][k] * B[n][k] (+bias) ----------------
// 128x128 tile, BK=64 (16 two-barrier iters), 4 waves x 64x64 quadrant.
// XCD-aware mapping: mode 0 (Q,K: A big) -> each XCD owns 4 mb + all nb.
// mode 1 (V: B big) -> each XCD owns 4 nb + all mb.
// LDS tiles are XOR-swizzled (chunk c stored at slot c^(row&7)) so fragment
// ds_read_b128s spread across all bank quads (2-way = free) despite the
// 128B row stride. Epilogue repacks C through LDS for 16B coalesced stores.
struct GemmCfg {
  const bf16_t* A;
  const bf16_t* Bm;
  void* out;
  const float* bias;
  int mode;
};

union GemmSmem {
  struct { bf16_t A[128 * 64]; bf16_t B[128 * 64]; } ab;  // 32 KB
  bf16_t C[128 * 136];                                    // 34 KB
};

__global__ __launch_bounds__(256, 3) void gemm_nt_kernel(GemmCfg c0, GemmCfg c1, GemmCfg c2, int K) {
  GemmCfg cfg = (blockIdx.y == 0) ? c0 : (blockIdx.y == 1 ? c1 : c2);
  __shared__ GemmSmem u;
  __shared__ float bias_s[128];
  const int tid = threadIdx.x;
  const int wave = tid >> 6;
  const int lane = tid & 63;
  const int g = lane >> 4;
  const int cl = lane & 15;
  const int mq = (wave & 1) * 64;
  const int nq = (wave >> 1) * 64;

  const int xcd = blockIdx.x & 7, idx = blockIdx.x >> 3;
  int mb, nb;
  if (cfg.mode == 0) { mb = xcd * 4 + (idx & 3); nb = idx >> 2; }
  else               { nb = xcd * 4 + (idx & 3); mb = idx >> 2; }
  const int m0 = mb * 128, n0 = nb * 128;

  if (tid < 128) bias_s[tid] = cfg.bias[(cfg.mode == 0 ? n0 : m0) + tid];

  // staging: thread tid covers row (tid>>3) of each 32-row slab; it FETCHES
  // global chunk (tid&7)^(row&7) into linear LDS slot (tid&7).
  const int srow = tid >> 3;
  const int sch = (tid & 7) ^ (srow & 7);
  const bf16_t* Ag = cfg.A + (size_t)(m0 + srow) * K + sch * 8;
  const bf16_t* Bg = cfg.Bm + (size_t)(n0 + srow) * K + sch * 8;
  const int swz = cl & 7;  // reader swizzle key (row&7 == cl&7 for 16-strided rows)

  floatx4 acc[4][4];
#pragma unroll
  for (int i = 0; i < 4; ++i)
#pragma unroll
    for (int j = 0; j < 4; ++j) acc[i][j] = floatx4{0.f, 0.f, 0.f, 0.f};

  const int kiters = K >> 6;
  for (int kt = 0; kt < kiters; ++kt) {
    __syncthreads();
#pragma unroll
    for (int i = 0; i < 4; ++i) {
      __builtin_amdgcn_global_load_lds((g_u32_t*)(const void*)(Ag + (size_t)(i * 32) * K),
                                       (lds_u32_t*)(void*)&u.ab.A[(i * 256 + tid) * 8], 16, 0, 0);
      __builtin_amdgcn_global_load_lds((g_u32_t*)(const void*)(Bg + (size_t)(i * 32) * K),
                                       (lds_u32_t*)(void*)&u.ab.B[(i * 256 + tid) * 8], 16, 0, 0);
    }
    Ag += 64;
    Bg += 64;
    __syncthreads();

#pragma unroll
    for (int kc = 0; kc < 2; ++kc) {
      bf16x8 af[4], bfr[4];
#pragma unroll
      for (int i = 0; i < 4; ++i)
        af[i] = *(const bf16x8*)&u.ab.A[(mq + i * 16 + cl) * 64 + ((kc * 4 + g) ^ swz) * 8];
#pragma unroll
      for (int j = 0; j < 4; ++j)
        bfr[j] = *(const bf16x8*)&u.ab.B[(nq + j * 16 + cl) * 64 + ((kc * 4 + g) ^ swz) * 8];
#pragma unroll
      for (int i = 0; i < 4; ++i)
#pragma unroll
        for (int j = 0; j < 4; ++j) acc[i][j] = MFMA_BF16(af[i], bfr[j], acc[i][j]);
    }
  }

  // epilogue: quadrants -> LDS (with bias), then cooperative 16B coalesced stores
  __syncthreads();
#pragma unroll
  for (int i = 0; i < 4; ++i)
#pragma unroll
    for (int j = 0; j < 4; ++j)
#pragma unroll
      for (int r = 0; r < 4; ++r) {
        const int ml = mq + i * 16 + g * 4 + r;
        const int nl = nq + j * 16 + cl;
        float v = acc[i][j][r] + bias_s[cfg.mode == 0 ? nl : ml];
        u.C[ml * 136 + nl] = (bf16_t)v;
      }
  __syncthreads();
#pragma unroll
  for (int it = 0; it < 8; ++it) {
    const int ix = it * 256 + tid;
    const int ml = ix >> 4, nc = ix & 15;
    bf16x8 val = *(const bf16x8*)&u.C[ml * 136 + nc * 8];
    const int m = m0 + ml, n = n0 + nc * 8;
    size_t addr;
    if (cfg.mode == 0)
      addr = (size_t)((m >> 10) * 16 + (n >> 6)) * 65536 + (m & 1023) * 64 + (n & 63);
    else
      addr = (size_t)((n >> 10) * 16 + (m >> 6)) * 65536 + (m & 63) * 1024 + (n & 1023);
    *(bf16x8*)&((bf16_t*)cfg.out)[addr] = val;
  }
}

// ---------------- fused attention, GEMM-style LDS staging ----------------
// grid 512 = 8 q-tiles(128) x 64 (b,h): all q-tiles of one bh land on XCD bh%8.
// Block: 128 q-rows, 4 waves x 32 q-rows. Per k-tile (128 keys):
//   stage K[128x64] and Vt[64x128] into LDS (global_load_lds w16, XOR-swizzled
//   chunks so ds_read_b128 frags spread across bank quads), 2-barrier m97 loop.
//   S^T = K@Q^T (Q stays in registers as B-frags), exp -> P (per-wave LDS,
//   packed b64 writes), then O += P@V and O2 += mask@V from LDS/global.
// out = O/rowsum(P) + O2. No max-subtraction: logits ~ N(0,0.25), exp safe.
__global__ __launch_bounds__(256, 2) void attn_kernel(const bf16_t* __restrict__ Q,
                                                      const bf16_t* __restrict__ Kb,
                                                      const bf16_t* __restrict__ Vt,
                                                      const bf16_t* __restrict__ Mk,
                                                      float* __restrict__ out) {
  __shared__ bf16_t Ks[128 * 64];        // 16 KB
  __shared__ bf16_t Vs[64 * 128];        // 16 KB
  __shared__ bf16_t Pbuf[4][32 * 136];   // 34 KB, stride 136 = 17x16B (aligned, quad-spread)
  const int tid = threadIdx.x;
  const int wave = tid >> 6, lane = tid & 63;
  const int g = lane >> 4, cl = lane & 15;
  const int bh = blockIdx.x & 63, qt = blockIdx.x >> 6;
  const int q0w = qt * 128 + wave * 32;
  const bf16_t* Qp = Q + (size_t)bh * (S * HD);
  const bf16_t* Kp = Kb + (size_t)bh * (S * HD);
  const bf16_t* Vp = Vt + (size_t)bh * (S * HD);
  bf16_t* Pw = &Pbuf[wave][0];

  // staging: thread tid fills LDS slot (i*256+tid)*16B; it FETCHES the global
  // chunk c = c' ^ (row&7) so readers find data chunk cw at slot cw ^ (row&7).
  const int krow = tid >> 3, kch = (tid & 7) ^ (krow & 7);
  const int vrow = tid >> 4, vch = (tid & 15) ^ (vrow & 7);
  const int sw = cl & 7;  // reader-side swizzle key (row&7 == cl&7 for 16-strided rows)

  // Q B-frags, resident in registers for the whole kernel
  bf16x8 qf[2][2];
#pragma unroll
  for (int nj = 0; nj < 2; ++nj)
#pragma unroll
    for (int kc = 0; kc < 2; ++kc)
      qf[nj][kc] = *(const bf16x8*)&Qp[(size_t)(q0w + nj * 16 + cl) * HD + kc * 32 + g * 8];

  floatx4 o[2][4], o2[2][4];
#pragma unroll
  for (int mi = 0; mi < 2; ++mi)
#pragma unroll
    for (int nj = 0; nj < 4; ++nj) {
      o[mi][nj] = floatx4{0.f, 0.f, 0.f, 0.f};
      o2[mi][nj] = floatx4{0.f, 0.f, 0.f, 0.f};
    }
  float dsq[2] = {0.f, 0.f};

  for (int kt = 0; kt < 8; ++kt) {
    const int k0 = kt * 128;
    __syncthreads();
#pragma unroll
    for (int i = 0; i < 4; ++i)
      __builtin_amdgcn_global_load_lds(
          (g_u32_t*)(const void*)&Kp[(size_t)(k0 + i * 32 + krow) * HD + kch * 8],
          (lds_u32_t*)(void*)&Ks[(i * 256 + tid) * 8], 16, 0, 0);
#pragma unroll
    for (int i = 0; i < 4; ++i)
      __builtin_amdgcn_global_load_lds(
          (g_u32_t*)(const void*)&Vp[(size_t)(i * 16 + vrow) * S + k0 + vch * 8],
          (lds_u32_t*)(void*)&Vs[(i * 256 + tid) * 8], 16, 0, 0);
    __syncthreads();

    // S^T[k][q] = K @ Q^T ; exp ; packed b64 write into P[q][k]
#pragma unroll
    for (int mi = 0; mi < 8; ++mi) {
      bf16x8 kf0 = *(const bf16x8*)&Ks[(mi * 16 + cl) * 64 + ((0 + g) ^ sw) * 8];
      bf16x8 kf1 = *(const bf16x8*)&Ks[(mi * 16 + cl) * 64 + ((4 + g) ^ sw) * 8];
      floatx4 s0 = floatx4{0.f, 0.f, 0.f, 0.f}, s1 = floatx4{0.f, 0.f, 0.f, 0.f};
      s0 = MFMA_BF16(kf0, qf[0][0], s0);
      s0 = MFMA_BF16(kf1, qf[0][1], s0);
      s1 = MFMA_BF16(kf0, qf[1][0], s1);
      s1 = MFMA_BF16(kf1, qf[1][1], s1);
      bf16x4 p0, p1;
#pragma unroll
      for (int r = 0; r < 4; ++r) {
        float e0 = __expf(s0[r] * 0.03125f);
        float e1 = __expf(s1[r] * 0.03125f);
        dsq[0] += e0;
        dsq[1] += e1;
        p0[r] = (bf16_t)e0;
        p1[r] = (bf16_t)e1;
      }
      *(bf16x4*)&Pw[(cl)*136 + mi * 16 + g * 4] = p0;
      *(bf16x4*)&Pw[(16 + cl) * 136 + mi * 16 + g * 4] = p1;
    }

    // O += P @ V ; O2 += mask @ V
#pragma unroll
    for (int kc = 0; kc < 4; ++kc) {
      bf16x8 pa0 = *(const bf16x8*)&Pw[cl * 136 + kc * 32 + g * 8];
      bf16x8 pa1 = *(const bf16x8*)&Pw[(16 + cl) * 136 + kc * 32 + g * 8];
      bf16x8 ma0 = *(const bf16x8*)&Mk[(size_t)(q0w + cl) * S + k0 + kc * 32 + g * 8];
      bf16x8 ma1 = *(const bf16x8*)&Mk[(size_t)(q0w + 16 + cl) * S + k0 + kc * 32 + g * 8];
#pragma unroll
      for (int nj = 0; nj < 4; ++nj) {
        bf16x8 vf = *(const bf16x8*)&Vs[(nj * 16 + cl) * 128 + ((kc * 4 + g) ^ sw) * 8];
        o[0][nj] = MFMA_BF16(pa0, vf, o[0][nj]);
        o[1][nj] = MFMA_BF16(pa1, vf, o[1][nj]);
        o2[0][nj] = MFMA_BF16(ma0, vf, o2[0][nj]);
        o2[1][nj] = MFMA_BF16(ma1, vf, o2[1][nj]);
      }
    }
  }

  // denominator: lane (g,cl) holds partial sums for q=nj*16+cl over its k-slice;
  // combine the 4 g-copies, then redistribute to the C-layout rows via shfl.
#pragma unroll
  for (int nj = 0; nj < 2; ++nj) {
    dsq[nj] += __shfl_xor(dsq[nj], 16, 64);
    dsq[nj] += __shfl_xor(dsq[nj], 32, 64);
  }

  const int b = bh >> 4, h = bh & 15;
#pragma unroll
  for (int mi = 0; mi < 2; ++mi) {
#pragma unroll
    for (int r = 0; r < 4; ++r) {
      float dv = __shfl(dsq[mi], g * 4 + r, 64);  // lane g*4+r holds denom(q = mi*16+g*4+r)
      float dinv = 1.0f / dv;
      const int srow = q0w + mi * 16 + g * 4 + r;
#pragma unroll
      for (int nj = 0; nj < 4; ++nj) {
        const int hd = nj * 16 + cl;
        out[((size_t)b * S + srow) * 1024 + h * HD + hd] = o[mi][nj][r] * dinv + o2[mi][nj][r];
      }
    }
  }
}

extern "C" void kernel_launch(void* const* d_in, const int* in_sizes, int n_in,
                              void* d_out, int out_size, void* d_ws, size_t ws_size,
                              hipStream_t stream) {
  const float* x = (const float*)d_in[0];
  const float* y = (const float*)d_in[1];
  const float* z = (const float*)d_in[2];
  const float* mask = (const float*)d_in[3];
  const float* wq_w = (const float*)d_in[4];
  const float* wq_b = (const float*)d_in[5];
  const float* wk_w = (const float*)d_in[6];
  const float* wk_b = (const float*)d_in[7];
  const float* wv_w = (const float*)d_in[8];
  const float* wv_b = (const float*)d_in[9];

  uint8_t* ws = (uint8_t*)d_ws;
  const size_t MB = 1u << 20;
  bf16_t* Xb = (bf16_t*)(ws + 0 * MB);
  bf16_t* Yb = (bf16_t*)(ws + 8 * MB);
  bf16_t* Zb = (bf16_t*)(ws + 16 * MB);
  bf16_t* Wqb = (bf16_t*)(ws + 24 * MB);
  bf16_t* Wkb = (bf16_t*)(ws + 26 * MB);
  bf16_t* Wvb = (bf16_t*)(ws + 28 * MB);
  bf16_t* Mb = (bf16_t*)(ws + 30 * MB);
  bf16_t* Qb = (bf16_t*)(ws + 32 * MB);   // (b,h,s,hd) bf16
  bf16_t* Kb = (bf16_t*)(ws + 40 * MB);   // (b,h,s,hd) bf16
  bf16_t* Vtb = (bf16_t*)(ws + 48 * MB);  // (b,h,hd,s) bf16

  ConvArgs ca;
  ca.src[0] = x;    ca.dst[0] = Xb;  ca.n[0] = 4 * 1024 * 1024;
  ca.src[1] = y;    ca.dst[1] = Yb;  ca.n[1] = 4 * 1024 * 1024;
  ca.src[2] = z;    ca.dst[2] = Zb;  ca.n[2] = 4 * 1024 * 1024;
  ca.src[3] = wq_w; ca.dst[3] = Wqb; ca.n[3] = 1024 * 1024;
  ca.src[4] = wk_w; ca.dst[4] = Wkb; ca.n[4] = 1024 * 1024;
  ca.src[5] = wv_w; ca.dst[5] = Wvb; ca.n[5] = 1024 * 1024;
  ca.src[6] = mask; ca.dst[6] = Mb;  ca.n[6] = 1024 * 1024;
  convert_kernel<<<dim3(512, 7), 256, 0, stream>>>(ca);

  // Q = x@Wq^T (mode 0), K = y@Wk^T (mode 0), Vt = Wv@z^T (mode 1, transposed output)
  GemmCfg cq{Xb, Wqb, (void*)Qb, wq_b, 0};
  GemmCfg ck{Yb, Wkb, (void*)Kb, wk_b, 0};
  GemmCfg cv{Wvb, Zb, (void*)Vtb, wv_b, 1};
  gemm_nt_kernel<<<dim3(256, 3), 256, 0, stream>>>(cq, ck, cv, 1024);

  attn_kernel<<<dim3(512), 256, 0, stream>>>(Qb, Kb, Vtb, Mb, (float*)d_out);
}